// Round 4
// baseline (1877.737 us; speedup 1.0000x reference)
//
#include <hip/hip_runtime.h>

using half8 = __attribute__((ext_vector_type(8))) _Float16;
using half4 = __attribute__((ext_vector_type(4))) _Float16;
using f32x4 = __attribute__((ext_vector_type(4))) float;

// ws layout (bytes)
#define OFF_XPROJ 0ULL                 // 8192*2048*2  = 33554432
#define OFF_WHH   33554432ULL          // 2048*512*2   = 2097152
#define OFF_WC    35651584ULL          // 2048*256*2   = 1048576
#define OFF_WCF32 36700160ULL          // 2048*256*4   = 2097152
#define OFF_BC    38797312ULL          // 2048*4
#define OFF_B0    38805504ULL          // 2048*4

__device__ __forceinline__ float sigm(float x){ return 1.0f/(1.0f + __expf(-x)); }
__device__ __forceinline__ float tanh_(float x){ float e = __expf(2.0f*x); return 1.0f - 2.0f/(e + 1.0f); }

// ---------------- prep1: Wc = w_ih @ conv_w (fp32), combined biases (permuted) ----
__global__ void prep1(const float* __restrict__ conv_w, const float* __restrict__ conv_b,
                      const float* __restrict__ w_ih, const float* __restrict__ b_ih,
                      const float* __restrict__ b_hh, float* __restrict__ Wc,
                      float* __restrict__ bc_perm, float* __restrict__ b0_perm){
  int bid = blockIdx.x, t = threadIdx.x;
  if (bid < 1024) {
    int r0 = bid*2;
    float a0 = 0.f, a1 = 0.f;
    const float* w0 = w_ih + (size_t)r0*512;
    for (int d=0; d<512; ++d){
      float cw = conv_w[d*256 + t];
      a0 = fmaf(w0[d],     cw, a0);
      a1 = fmaf(w0[512+d], cw, a1);
    }
    Wc[(size_t)r0*256 + t]     = a0;
    Wc[(size_t)(r0+1)*256 + t] = a1;
  } else {
    int r = (bid-1024)*256 + t;          // 0..2047
    float s = 0.f;
    for (int d=0; d<512; ++d) s = fmaf(w_ih[(size_t)r*512+d], conv_b[d], s);
    int gate = r >> 9, u = r & 511;
    int newc = ((u>>4)<<6) + (gate<<4) + (u&15);
    float bb = b_ih[r] + b_hh[r];
    b0_perm[newc] = bb;          // padded-step bias (no conv_b term!)
    bc_perm[newc] = s + bb;      // in-bounds bias (conv_b folded through w_ih)
  }
}

// ---------------- prep2: swizzle w_hh and Wc into MFMA B-fragment order (fp16) ----
__global__ void prep2(const float* __restrict__ w_hh, const float* __restrict__ Wc,
                      _Float16* __restrict__ whh_f, _Float16* __restrict__ wc_f){
  int e = blockIdx.x*256 + threadIdx.x;     // 6144*256 = 2^20 + 2^19 exactly
  if (e < (1<<20)) {
    int j = e&7, lane = (e>>3)&63, t = (e>>9)&127, s = e>>16;   // s: 0..15
    int newc = t*16 + (lane&15);
    int k = s*32 + (lane>>4)*8 + j;
    int r = (((newc>>4)&3)<<9) + ((newc>>6)<<4) + (newc&15);
    whh_f[e] = (_Float16)w_hh[r*512 + k];
  } else {
    int e2 = e - (1<<20);
    int j = e2&7, lane = (e2>>3)&63, t = (e2>>9)&127, s = e2>>16; // s: 0..7
    int newc = t*16 + (lane&15);
    int k = s*32 + (lane>>4)*8 + j;
    int r = (((newc>>4)&3)<<9) + ((newc>>6)<<4) + (newc&15);
    wc_f[e2] = (_Float16)Wc[r*256 + k];
  }
}

// ---------------- xp: xproj = glu(x) @ Wc.T + bc  (fp16 out, permuted cols) -------
// Non-temporal x loads and xproj stores: keep wc_f resident in L2.
__global__ __launch_bounds__(512, 2) void xp_kernel(const float* __restrict__ x,
      const _Float16* __restrict__ wc_f, const float* __restrict__ bc_perm,
      _Float16* __restrict__ xproj){
  __shared__ _Float16 A[32*264];            // 32 rows x 256, pitch 264
  int wg = blockIdx.x, tid = threadIdx.x;
  int n0 = wg*32;
  int wv = tid>>6, lane = tid&63, lrow = lane>>4, lcol = lane&15;
  #pragma unroll
  for (int i=0;i<4;++i){
    int q = tid + i*512;                    // 0..2047
    int row = q>>6, pos = q&63;
    const float* xr = x + (size_t)(n0+row)*512;
    f32x4 va = __builtin_nontemporal_load((const f32x4*)(xr + pos*4));
    f32x4 vb = __builtin_nontemporal_load((const f32x4*)(xr + 256 + pos*4));
    half4 h;
    h[0] = (_Float16)(va[0] / (1.f+__expf(-vb[0])));
    h[1] = (_Float16)(va[1] / (1.f+__expf(-vb[1])));
    h[2] = (_Float16)(va[2] / (1.f+__expf(-vb[2])));
    h[3] = (_Float16)(va[3] / (1.f+__expf(-vb[3])));
    *(half4*)&A[row*264 + pos*4] = h;
  }
  f32x4 acc[2][16];
  #pragma unroll
  for (int nt=0;nt<16;++nt){
    int col = (wv*16+nt)*16 + lcol;
    float b = bc_perm[col];
    f32x4 v = {b,b,b,b};
    acc[0][nt]=v; acc[1][nt]=v;
  }
  __syncthreads();
  for (int s=0;s<8;++s){
    half8 a0 = *(const half8*)&A[lcol*264 + s*32 + lrow*8];
    half8 a1 = *(const half8*)&A[(16+lcol)*264 + s*32 + lrow*8];
    #pragma unroll
    for (int nt=0;nt<16;++nt){
      int t = wv*16+nt;
      half8 b = *(const half8*)(wc_f + ((s*128 + t)*64 + lane)*8);
      acc[0][nt] = __builtin_amdgcn_mfma_f32_16x16x32_f16(a0, b, acc[0][nt], 0,0,0);
      acc[1][nt] = __builtin_amdgcn_mfma_f32_16x16x32_f16(a1, b, acc[1][nt], 0,0,0);
    }
  }
  #pragma unroll
  for (int m=0;m<2;++m)
    #pragma unroll
    for (int nt=0;nt<16;++nt){
      int col = (wv*16+nt)*16 + lcol;
      #pragma unroll
      for (int reg=0;reg<4;++reg){
        int n = n0 + m*16 + lrow*4 + reg;
        __builtin_nontemporal_store((_Float16)acc[m][nt][reg], &xproj[(size_t)n*2048 + col]);
      }
    }
}

// ---------------- lstm v2: two gate-passes/step, dbuf b-frags, nt xproj ----------
// Pass A computes gates i,f (cols with (nt&3)<2); sigm() results stay thread-private
// in packed fp16 regs (the gate-interleaved permutation makes writer==reader).
// Pass B computes g,o then does the elementwise update.

#define GATHER(ACC, P2, B0) { \
  _Pragma("unroll") for (int m=0;m<2;++m){ \
  _Pragma("unroll") for (int j=0;j<8;++j){ \
    int col = (tb + ((j>>1)<<2) + (P2) + (j&1))*16 + lcol; \
    _Pragma("unroll") for (int reg=0;reg<4;++reg){ \
      int rl = m*16 + lrow*4 + reg; \
      int lx = l0 + rl + k - 8; \
      const _Float16* p = xproj + (size_t)((lx<0)? n0 : (n0 + rl + k - 8))*2048 + col; \
      float xv = (float)__builtin_nontemporal_load(p); \
      ACC[m][j][reg] = (lx < 0) ? (B0)[j] : xv; \
    } } } }

#define LOADB(BUF, S, P2) { \
  _Pragma("unroll") for (int j=0;j<8;++j){ \
    int cj = ((j>>1)<<2) + (P2) + (j&1); \
    BUF[j] = *(const half8*)(whh_base + ((size_t)(S)*128 + cj)*512); } }

#define MFMAS(BUF, S) { \
    half8 a0 = *(const half8*)&H[lcol*520 + (S)*32 + lrow*8]; \
    half8 a1 = *(const half8*)&H[(16+lcol)*520 + (S)*32 + lrow*8]; \
    _Pragma("unroll") for (int j=0;j<8;++j){ \
      acc[0][j] = __builtin_amdgcn_mfma_f32_16x16x32_f16(a0, BUF[j], acc[0][j],0,0,0); \
      acc[1][j] = __builtin_amdgcn_mfma_f32_16x16x32_f16(a1, BUF[j], acc[1][j],0,0,0); } }

#define GEMM(P2) { \
    half8 e0[8], e1[8]; \
    LOADB(e0, 0, P2) \
    _Pragma("unroll") for (int ss=0; ss<7; ++ss){ \
      LOADB(e1, 2*ss+1, P2) MFMAS(e0, 2*ss) \
      LOADB(e0, 2*ss+2, P2) MFMAS(e1, 2*ss+1) \
    } \
    LOADB(e1, 15, P2) MFMAS(e0, 14) MFMAS(e1, 15) }

__global__ __launch_bounds__(512, 2) void lstm_kernel(const _Float16* __restrict__ xproj,
      const _Float16* __restrict__ whh_f, const float* __restrict__ b0_perm,
      float* __restrict__ out){
  __shared__ _Float16 H[32*520];            // pitch 520 (16B-aligned rows)
  int wg = blockIdx.x, tid = threadIdx.x;
  int n0 = wg*32, l0 = n0 & 511;
  int wv = tid>>6, lane = tid&63, lrow = lane>>4, lcol = lane&15;
  int tb = wv*16;                           // wave's global N-tile base
  const _Float16* whh_base = whh_f + ((size_t)tb*64 + lane)*8;

  f32x4 c[2][4];
  #pragma unroll
  for (int m=0;m<2;++m)
    #pragma unroll
    for (int g=0;g<4;++g) c[m][g] = (f32x4){0.f,0.f,0.f,0.f};

  float b0A[8], b0B[8];
  #pragma unroll
  for (int j=0;j<8;++j){
    int g = j>>1, gate = j&1;
    b0A[j] = b0_perm[(tb + g*4 + gate)*16 + lcol];
    b0B[j] = b0_perm[(tb + g*4 + 2 + gate)*16 + lcol];
  }

  #pragma unroll 1
  for (int k=0;k<9;++k){
    f32x4 acc[2][8];
    // ---- pass A: gates i,f ----
    GATHER(acc, 0, b0A)
    if (k > 0) GEMM(0)
    half4 siP[2][4], sfP[2][4];
    #pragma unroll
    for (int m=0;m<2;++m)
      #pragma unroll
      for (int g=0;g<4;++g){
        half4 si, sf;
        #pragma unroll
        for (int reg=0;reg<4;++reg){
          si[reg] = (_Float16)sigm(acc[m][g*2+0][reg]);
          sf[reg] = (_Float16)sigm(acc[m][g*2+1][reg]);
        }
        siP[m][g] = si; sfP[m][g] = sf;
      }
    // ---- pass B: gates g,o ----
    GATHER(acc, 2, b0B)
    if (k > 0) GEMM(2)
    __syncthreads();   // all waves done reading H
    // ---- elementwise update ----
    #pragma unroll
    for (int m=0;m<2;++m)
      #pragma unroll
      for (int g=0;g<4;++g){
        #pragma unroll
        for (int reg=0;reg<4;++reg){
          float gg = acc[m][g*2+0][reg], go = acc[m][g*2+1][reg];
          float si = (float)siP[m][g][reg], sf = (float)sfP[m][g][reg];
          float cn = sf*c[m][g][reg] + si*tanh_(gg);
          c[m][g][reg] = cn;
          float h = sigm(go)*tanh_(cn);
          int row = m*16 + lrow*4 + reg;
          int u = ((tb>>2)+g)*16 + lcol;
          if (k < 8) H[row*520 + u] = (_Float16)h;
          else __builtin_nontemporal_store(h, &out[(size_t)(n0+row)*512 + u]);
        }
      }
    __syncthreads();
  }
}

extern "C" void kernel_launch(void* const* d_in, const int* in_sizes, int n_in,
                              void* d_out, int out_size, void* d_ws, size_t ws_size,
                              hipStream_t stream){
  const float* x      = (const float*)d_in[0];
  const float* conv_w = (const float*)d_in[1];
  const float* conv_b = (const float*)d_in[2];
  const float* w_ih   = (const float*)d_in[3];
  const float* w_hh   = (const float*)d_in[4];
  const float* b_ih   = (const float*)d_in[5];
  const float* b_hh   = (const float*)d_in[6];
  char* ws = (char*)d_ws;
  _Float16* xproj = (_Float16*)(ws + OFF_XPROJ);
  _Float16* whh_f = (_Float16*)(ws + OFF_WHH);
  _Float16* wc_f  = (_Float16*)(ws + OFF_WC);
  float* Wc       = (float*)(ws + OFF_WCF32);
  float* bc_perm  = (float*)(ws + OFF_BC);
  float* b0_perm  = (float*)(ws + OFF_B0);
  float* out = (float*)d_out;

  prep1<<<1032, 256, 0, stream>>>(conv_w, conv_b, w_ih, b_ih, b_hh, Wc, bc_perm, b0_perm);
  prep2<<<6144, 256, 0, stream>>>(w_hh, Wc, whh_f, wc_f);
  xp_kernel<<<256, 512, 0, stream>>>(x, wc_f, bc_perm, xproj);
  lstm_kernel<<<256, 512, 0, stream>>>(xproj, whh_f, b0_perm, out);
}

// Round 5
// 565.138 us; speedup vs baseline: 3.3226x; 3.3226x over previous
//
#include <hip/hip_runtime.h>
#include <stdint.h>

using half8 = __attribute__((ext_vector_type(8))) _Float16;
using half4 = __attribute__((ext_vector_type(4))) _Float16;
using f32x4 = __attribute__((ext_vector_type(4))) float;

// ws layout (bytes)
#define OFF_XPROJT 0ULL                  // 2048 cols * 8320 slots * 2B = 34078720
#define OFF_WHH    34078720ULL           // 2048*512*2 = 2097152
#define OFF_WCF    36175872ULL           // 2048*256*2 = 1048576
#define OFF_BC     37224448ULL           // 2048*4
#define OFF_B0     37232640ULL           // 2048*4
// Wc fp32 (2 MB) aliased at offset 0 — dead after prep2; prefill/xp overwrite later.

__device__ __forceinline__ float sigm(float x){ return 1.0f/(1.0f + __expf(-x)); }
__device__ __forceinline__ float tanh_(float x){ float e = __expf(2.0f*x); return 1.0f - 2.0f/(e + 1.0f); }

// ---------------- prep1: Wc = w_ih @ conv_w (fp32), combined biases (permuted) ----
__global__ void prep1(const float* __restrict__ conv_w, const float* __restrict__ conv_b,
                      const float* __restrict__ w_ih, const float* __restrict__ b_ih,
                      const float* __restrict__ b_hh, float* __restrict__ Wc,
                      float* __restrict__ bc_perm, float* __restrict__ b0_perm){
  int bid = blockIdx.x, t = threadIdx.x;
  if (bid < 1024) {
    int r0 = bid*2;
    float a0 = 0.f, a1 = 0.f;
    const float* w0 = w_ih + (size_t)r0*512;
    for (int d=0; d<512; ++d){
      float cw = conv_w[d*256 + t];
      a0 = fmaf(w0[d],     cw, a0);
      a1 = fmaf(w0[512+d], cw, a1);
    }
    Wc[(size_t)r0*256 + t]     = a0;
    Wc[(size_t)(r0+1)*256 + t] = a1;
  } else {
    int r = (bid-1024)*256 + t;          // 0..2047
    float s = 0.f;
    for (int d=0; d<512; ++d) s = fmaf(w_ih[(size_t)r*512+d], conv_b[d], s);
    int gate = r >> 9, u = r & 511;
    int newc = ((u>>4)<<6) + (gate<<4) + (u&15);
    float bbv = b_ih[r] + b_hh[r];
    b0_perm[newc] = bbv;         // padded-step bias (no conv_b term!)
    bc_perm[newc] = s + bbv;     // in-bounds bias (conv_b folded through w_ih)
  }
}

// ---------------- prep2: swizzle w_hh and Wc into MFMA B-fragment order (fp16) ----
__global__ void prep2(const float* __restrict__ w_hh, const float* __restrict__ Wc,
                      _Float16* __restrict__ whh_f, _Float16* __restrict__ wc_f){
  int e = blockIdx.x*256 + threadIdx.x;     // 6144*256 = 2^20 + 2^19 exactly
  if (e < (1<<20)) {
    int j = e&7, lane = (e>>3)&63, t = (e>>9)&127, s = e>>16;   // s: 0..15
    int newc = t*16 + (lane&15);
    int k = s*32 + (lane>>4)*8 + j;
    int r = (((newc>>4)&3)<<9) + ((newc>>6)<<4) + (newc&15);
    whh_f[e] = (_Float16)w_hh[r*512 + k];
  } else {
    int e2 = e - (1<<20);
    int j = e2&7, lane = (e2>>3)&63, t = (e2>>9)&127, s = e2>>16; // s: 0..7
    int newc = t*16 + (lane&15);
    int k = s*32 + (lane>>4)*8 + j;
    int r = (((newc>>4)&3)<<9) + ((newc>>6)<<4) + (newc&15);
    wc_f[e2] = (_Float16)Wc[r*256 + k];
  }
}

// ---------------- prefill: batch-boundary pad slots = b0 bias -------------------
__global__ void prefill(const float* __restrict__ b0_perm, _Float16* __restrict__ xprojT){
  int e = blockIdx.x*256 + threadIdx.x;     // 1024*256 = 2048*16*8
  int col = e>>7, b = (e>>3)&15, p = e&7;
  xprojT[(size_t)col*8320 + b*520 + p] = (_Float16)b0_perm[col];
}

// ---------------- xp: xprojT[col][b][8+l] = glu(x) @ Wc.T + bc  (fp16) ----------
__global__ __launch_bounds__(512, 2) void xp_kernel(const float* __restrict__ x,
      const _Float16* __restrict__ wc_f, const float* __restrict__ bc_perm,
      _Float16* __restrict__ xprojT){
  __shared__ _Float16 A[32*264];            // 32 rows x 256, pitch 264
  int wg = blockIdx.x, tid = threadIdx.x;
  int n0 = wg*32;
  int wv = tid>>6, lane = tid&63, lrow = lane>>4, lcol = lane&15;
  #pragma unroll
  for (int i=0;i<4;++i){
    int q = tid + i*512;                    // 0..2047
    int row = q>>6, pos = q&63;
    const float* xr = x + (size_t)(n0+row)*512;
    f32x4 va = __builtin_nontemporal_load((const f32x4*)(xr + pos*4));
    f32x4 vb = __builtin_nontemporal_load((const f32x4*)(xr + 256 + pos*4));
    half4 h;
    h[0] = (_Float16)(va[0] / (1.f+__expf(-vb[0])));
    h[1] = (_Float16)(va[1] / (1.f+__expf(-vb[1])));
    h[2] = (_Float16)(va[2] / (1.f+__expf(-vb[2])));
    h[3] = (_Float16)(va[3] / (1.f+__expf(-vb[3])));
    *(half4*)&A[row*264 + pos*4] = h;
  }
  f32x4 acc[2][16];
  #pragma unroll
  for (int nt=0;nt<16;++nt){
    int col = (wv*16+nt)*16 + lcol;
    float b = bc_perm[col];
    f32x4 v = {b,b,b,b};
    acc[0][nt]=v; acc[1][nt]=v;
  }
  __syncthreads();
  for (int s=0;s<8;++s){
    half8 a0 = *(const half8*)&A[lcol*264 + s*32 + lrow*8];
    half8 a1 = *(const half8*)&A[(16+lcol)*264 + s*32 + lrow*8];
    #pragma unroll
    for (int nt=0;nt<16;++nt){
      int t = wv*16+nt;
      half8 b = *(const half8*)(wc_f + ((s*128 + t)*64 + lane)*8);
      acc[0][nt] = __builtin_amdgcn_mfma_f32_16x16x32_f16(a0, b, acc[0][nt], 0,0,0);
      acc[1][nt] = __builtin_amdgcn_mfma_f32_16x16x32_f16(a1, b, acc[1][nt], 0,0,0);
    }
  }
  #pragma unroll
  for (int m=0;m<2;++m)
    #pragma unroll
    for (int nt=0;nt<16;++nt){
      int col = (wv*16+nt)*16 + lcol;
      int n = n0 + m*16 + lrow*4;
      half4 hv;
      hv[0]=(_Float16)acc[m][nt][0]; hv[1]=(_Float16)acc[m][nt][1];
      hv[2]=(_Float16)acc[m][nt][2]; hv[3]=(_Float16)acc[m][nt][3];
      *(half4*)&xprojT[(size_t)col*8320 + (size_t)(n>>9)*520 + 8 + (n&511)] = hv;
    }
}

// ---------------- lstm v3: whh DMA-staged via global_load_lds, counted vmcnt -----
// Per wave: private 2x4KB LDS chunk double-buffer; 64 chunks/step (16 s x 4 tile-
// groups); lookahead-1 issue with s_waitcnt vmcnt(4); no barriers inside s-loop.

#define ISSUE4(SP, GQ, BUF) { \
  const char* gp = whhB + ((((size_t)(SP))*128 + tb + (GQ)*4) << 10) + (lane<<4); \
  char* lpb = (char*)&CHUNK[wv][BUF][0]; \
  _Pragma("unroll") for (int jj=0;jj<4;++jj) \
    __builtin_amdgcn_global_load_lds((const __attribute__((address_space(1))) void*)(gp + (jj<<10)), \
        (__attribute__((address_space(3))) void*)(lpb + (jj<<10)), 16, 0, 0); }

#define GMFMA(G_) \
    _Pragma("unroll") for (int j=0;j<4;++j){ \
      half8 bf = *(const half8*)&CHUNK[wv][(G_)&1][j*1024 + lane*16]; \
      acc[0][(G_)*4+j] = __builtin_amdgcn_mfma_f32_16x16x32_f16(a0, bf, acc[0][(G_)*4+j],0,0,0); \
      acc[1][(G_)*4+j] = __builtin_amdgcn_mfma_f32_16x16x32_f16(a1, bf, acc[1][(G_)*4+j],0,0,0); }

#define GBODY_ISSUE(S_, G_) { \
    ISSUE4(((G_)<3 ? (S_) : (S_)+1), (((G_)+1)&3), (((G_)+1)&1)); \
    asm volatile("s_waitcnt vmcnt(4)" ::: "memory"); \
    __builtin_amdgcn_sched_barrier(0); \
    GMFMA(G_) }

#define GBODY_LAST(G_) { \
    asm volatile("s_waitcnt vmcnt(0)" ::: "memory"); \
    __builtin_amdgcn_sched_barrier(0); \
    GMFMA(G_) }

__global__ __launch_bounds__(512, 2) void lstm_kernel(const _Float16* __restrict__ xprojT,
      const _Float16* __restrict__ whh_f, float* __restrict__ out){
  __shared__ _Float16 H[32*520];                               // 33280 B, pitch 520
  __shared__ __attribute__((aligned(16))) char CHUNK[8][2][4096];  // 65536 B
  int wg = blockIdx.x, tid = threadIdx.x;
  int n0 = wg*32, l0 = n0 & 511, bb = n0 >> 9;
  int wv = tid>>6, lane = tid&63, lrow = lane>>4, lcol = lane&15;
  int tb = wv*16;
  const char* whhB = (const char*)whh_f;

  f32x4 c[2][4];
  #pragma unroll
  for (int m=0;m<2;++m)
    #pragma unroll
    for (int g=0;g<4;++g) c[m][g] = (f32x4){0.f,0.f,0.f,0.f};

  #pragma unroll 1
  for (int k=0;k<9;++k){
    f32x4 acc[2][16];
    // ---- gather input-projection gates from transposed xproj (bias baked in; ---
    // ---- batch pads prefilled with b0 -> no masking, any k) --------------------
    {
      int sh = (k&1)*16;                       // wave-uniform sub-dword shift
      size_t segb = (size_t)bb*520 + l0 + k;   // = b*520 + 8 + l0 + (k-8)
      #pragma unroll
      for (int m=0;m<2;++m)
        #pragma unroll
        for (int nt=0;nt<16;++nt){
          size_t S = (size_t)((tb+nt)*16 + lcol)*8320 + segb + m*16 + lrow*4;
          const uint32_t* p = (const uint32_t*)(xprojT + (S & ~(size_t)1));
          uint32_t d0 = p[0], d1 = p[1], d2 = p[2];
          uint32_t lo = __builtin_amdgcn_alignbit(d1, d0, sh);
          uint32_t hi = __builtin_amdgcn_alignbit(d2, d1, sh);
          union { uint32_t u; _Float16 h[2]; } ua, ub;
          ua.u = lo; ub.u = hi;
          acc[m][nt] = (f32x4){(float)ua.h[0], (float)ua.h[1], (float)ub.h[0], (float)ub.h[1]};
        }
    }
    __builtin_amdgcn_sched_barrier(0);
    // ---- recurrent GEMM: gates += h @ w_hh.T (skip at k==0) --------------------
    if (k > 0){
      ISSUE4(0, 0, 0);                         // prologue: chunk (s=0,g=0) -> buf0
      #pragma unroll 1
      for (int s=0;s<15;++s){
        half8 a0 = *(const half8*)&H[lcol*520 + s*32 + lrow*8];
        half8 a1 = *(const half8*)&H[(16+lcol)*520 + s*32 + lrow*8];
        GBODY_ISSUE(s,0) GBODY_ISSUE(s,1) GBODY_ISSUE(s,2) GBODY_ISSUE(s,3)
      }
      {
        half8 a0 = *(const half8*)&H[lcol*520 + 15*32 + lrow*8];
        half8 a1 = *(const half8*)&H[(16+lcol)*520 + 15*32 + lrow*8];
        GBODY_ISSUE(15,0) GBODY_ISSUE(15,1) GBODY_ISSUE(15,2) GBODY_LAST(3)
      }
    }
    __syncthreads();   // all waves done reading H before it is overwritten
    // ---- elementwise LSTM update: i,f,g,o = 4 adjacent N-tiles, same lane/reg --
    #pragma unroll
    for (int m=0;m<2;++m)
      #pragma unroll
      for (int ub=0;ub<4;++ub){
        f32x4 gi = acc[m][ub*4+0], gf = acc[m][ub*4+1];
        f32x4 gg = acc[m][ub*4+2], go = acc[m][ub*4+3];
        #pragma unroll
        for (int reg=0;reg<4;++reg){
          float cn = sigm(gf[reg])*c[m][ub][reg] + sigm(gi[reg])*tanh_(gg[reg]);
          c[m][ub][reg] = cn;
          float h = sigm(go[reg])*tanh_(cn);
          int row = m*16 + lrow*4 + reg;
          int u = (wv*4+ub)*16 + lcol;
          if (k < 8) H[row*520 + u] = (_Float16)h;
          else __builtin_nontemporal_store(h, &out[(size_t)(n0+row)*512 + u]);
        }
      }
    __syncthreads();
  }
}

extern "C" void kernel_launch(void* const* d_in, const int* in_sizes, int n_in,
                              void* d_out, int out_size, void* d_ws, size_t ws_size,
                              hipStream_t stream){
  const float* x      = (const float*)d_in[0];
  const float* conv_w = (const float*)d_in[1];
  const float* conv_b = (const float*)d_in[2];
  const float* w_ih   = (const float*)d_in[3];
  const float* w_hh   = (const float*)d_in[4];
  const float* b_ih   = (const float*)d_in[5];
  const float* b_hh   = (const float*)d_in[6];
  char* ws = (char*)d_ws;
  _Float16* xprojT = (_Float16*)(ws + OFF_XPROJT);
  _Float16* whh_f  = (_Float16*)(ws + OFF_WHH);
  _Float16* wc_f   = (_Float16*)(ws + OFF_WCF);
  float* Wc        = (float*)(ws + 0);       // aliased into xprojT region (transient)
  float* bc_perm   = (float*)(ws + OFF_BC);
  float* b0_perm   = (float*)(ws + OFF_B0);
  float* out = (float*)d_out;

  prep1<<<1032, 256, 0, stream>>>(conv_w, conv_b, w_ih, b_ih, b_hh, Wc, bc_perm, b0_perm);
  prep2<<<6144, 256, 0, stream>>>(w_hh, Wc, whh_f, wc_f);
  prefill<<<1024, 256, 0, stream>>>(b0_perm, xprojT);
  xp_kernel<<<256, 512, 0, stream>>>(x, wc_f, bc_perm, xprojT);
  lstm_kernel<<<256, 512, 0, stream>>>(xprojT, whh_f, out);
}